// Round 2
// 1784.296 us; speedup vs baseline: 1.0161x; 1.0161x over previous
//
#include <hip/hip_runtime.h>

// Shapes (fixed by the reference)
#define Bb 4
#define Hh 16
#define Ss 2048
#define Dd 128
#define KT 32          // k-tile columns per iteration
#define NIT (Ss / KT)  // 64 iterations per phase

typedef __bf16 bf16x8 __attribute__((ext_vector_type(8)));
typedef __bf16 bf16x4 __attribute__((ext_vector_type(4)));
typedef float f32x4 __attribute__((ext_vector_type(4)));

// ---------- prep: fp32 -> bf16 flat for Q and K ----------
__global__ void k_cvt(const float4* __restrict__ Q, const float4* __restrict__ K,
                      bf16x4* __restrict__ Qb, bf16x4* __restrict__ Kb) {
    size_t i = (size_t)blockIdx.x * 256 + threadIdx.x;
    float4 q = Q[i], k = K[i];
    Qb[i] = (bf16x4){(__bf16)q.x, (__bf16)q.y, (__bf16)q.z, (__bf16)q.w};
    Kb[i] = (bf16x4){(__bf16)k.x, (__bf16)k.y, (__bf16)k.z, (__bf16)k.w};
}

// ---------- prep: V fp32 [bh][k][d] -> bf16 V^T [bh][d][k] ----------
__global__ void k_vt(const float* __restrict__ V, __bf16* __restrict__ VT) {
    __shared__ __bf16 lds[64][65];
    int k0 = blockIdx.x * 64, d0 = blockIdx.y * 64, bh = blockIdx.z;
    int t = threadIdx.x;
    for (int i = 0; i < 16; ++i) {
        int idx = i * 256 + t;
        int kl = idx >> 6, dl = idx & 63;
        lds[kl][dl] = (__bf16)V[((size_t)(bh * Ss + k0 + kl)) * Dd + d0 + dl];
    }
    __syncthreads();
    for (int i = 0; i < 16; ++i) {
        int idx = i * 256 + t;
        int dl = idx >> 6, kl = idx & 63;
        VT[((size_t)(bh * Dd + d0 + dl)) * Ss + k0 + kl] = lds[kl][dl];
    }
}

// ---------- prep: mask fp32 [b][q][k] -> bits maskT[b][k][q/32] (bit=1 => masked) ----------
__global__ void k_mask(const float* __restrict__ M, unsigned* __restrict__ maskT) {
    __shared__ unsigned char lds[64][68];
    int k0 = blockIdx.x * 64, q0 = blockIdx.y * 64, b = blockIdx.z;
    int t = threadIdx.x;
    for (int i = 0; i < 16; ++i) {
        int idx = i * 256 + t;
        int ql = idx >> 6, kl = idx & 63;
        lds[ql][kl] = (M[((size_t)(b * Ss + q0 + ql)) * Ss + k0 + kl] != 0.0f) ? 1 : 0;
    }
    __syncthreads();
    if (t < 128) {
        int kl = t >> 1, wsel = t & 1;
        unsigned wv = 0;
        for (int j = 0; j < 32; ++j)
            wv |= ((unsigned)lds[wsel * 32 + j][kl]) << j;
        maskT[((size_t)(b * Ss + k0 + kl)) * (Ss / 32) + (q0 >> 5) + wsel] = wv;
    }
}

// async 16B global->LDS copy (LDS dest: wave-uniform base + lane*16)
__device__ __forceinline__ void gl2lds16(const void* g, void* l) {
    __builtin_amdgcn_global_load_lds(
        (const __attribute__((address_space(1))) unsigned int*)g,
        (__attribute__((address_space(3))) unsigned int*)l, 16, 0, 0);
}

// ---------- main fused attention ----------
// grid (32, 64), block 256 (4 waves). Each block: 64 q-rows, full K sweep x2.
// LDS = 2*8K (K dbuf) + 2*8K (V^T dbuf) + 8K (Ps) = 40960 B exactly -> 4 blocks/CU.
__global__ __launch_bounds__(256, 4) void attn_kernel(
    const __bf16* __restrict__ Qb, const __bf16* __restrict__ Kb,
    const __bf16* __restrict__ VTb, const unsigned* __restrict__ maskT,
    float* __restrict__ out, float* __restrict__ attn) {
    __shared__ __align__(16) __bf16 Ks[2][KT][Dd];   // 2 x 8192 B, XOR-swizzled contents
    __shared__ __align__(16) __bf16 VTs[2][Dd][KT];  // 2 x 8192 B, XOR-swizzled contents
    __shared__ __align__(16) __bf16 Ps[4][16][64];   // per-wave P bridge (32 cols, swizzled)

    const int t = threadIdx.x;
    const int w = t >> 6, lane = t & 63, quad = lane >> 4, l16 = lane & 15;

    // XCD-aware remap: 2048 wgs, 8 XCDs; XCD x gets bh in [8x,8x+8) with all 32 q-blocks
    const int wg = (int)blockIdx.x + ((int)blockIdx.y << 5);
    const int nid = ((wg & 7) << 8) + (wg >> 3);
    const int q0 = (nid & 31) << 6;
    const int bh = nid >> 5;
    const int b = bh >> 4;

    const __bf16* Kbh = Kb + (size_t)bh * (Ss * Dd);
    const char* Vbh = (const char*)(VTb + (size_t)bh * ((size_t)Dd * Ss));

    // staging geometry (linear LDS dest; inverse-swizzle applied to the GLOBAL source)
    const int ksub = t >> 4;                                   // K row within 16-row chunk
    const int kcb = ((t & 15) << 4) ^ ((ksub & 7) << 4);       // K source col bytes
    const int vsub = t >> 2;                                   // V row within 64-row chunk
    const int vcb = ((t & 3) << 4) ^ ((vsub & 3) << 4);        // V source col bytes
    char* ldsKbase = (char*)&Ks[0][0][0] + (w << 10);          // wave-uniform
    char* ldsVbase = (char*)&VTs[0][0][0] + (w << 10);

// buffer stride = 8192 B (<<13) — per-buffer size of Ks/VTs
#define STAGE_K(buf, k0_)                                                      \
    {                                                                          \
        const char* gb = (const char*)(Kbh + (size_t)(k0_) * Dd) + kcb;        \
        _Pragma("unroll") for (int i_ = 0; i_ < 2; ++i_)                       \
            gl2lds16(gb + ((i_ << 4) + ksub) * 256,                            \
                     ldsKbase + ((buf) << 13) + (i_ << 12));                   \
    }
#define STAGE_V(buf, k0_)                                                      \
    {                                                                          \
        const char* gb = Vbh + (size_t)(k0_) * 2 + vcb;                        \
        _Pragma("unroll") for (int i_ = 0; i_ < 2; ++i_)                       \
            gl2lds16(gb + (size_t)((i_ << 6) + vsub) * (Ss * 2),               \
                     ldsVbase + ((buf) << 13) + (i_ << 12));                   \
    }

    // Q fragments straight from global (no LDS staging for Q)
    bf16x8 aq[4];
    {
        STAGE_K(0, 0);
        const __bf16* qp =
            Qb + ((size_t)(bh * Ss + q0 + (w << 4) + l16)) * Dd + (quad << 3);
#pragma unroll
        for (int kd = 0; kd < 4; ++kd) aq[kd] = *(const bf16x8*)(qp + (kd << 5));
    }
    __syncthreads();  // drains vmcnt: K tile 0 resident

    const char* ldsK0 = (const char*)&Ks[0][0][0];
    const char* ldsV0 = (const char*)&VTs[0][0][0];
    const int kswz = (l16 & 7) << 4;
    const int vswz = (l16 & 3) << 4;

    const int qw = (q0 >> 5) + (w >> 1);
    const int bitbase = ((w & 1) << 4) + (quad << 2);
    const size_t mrowbase = (size_t)b * Ss * (Ss / 32);

    // ---- phase 1: row sums of exp(scores), prefetch-1-ahead ----
    float rsum[4] = {0.f, 0.f, 0.f, 0.f};
    for (int it = 0; it < NIT; ++it) {
        const int cur = it & 1;
        if (it < NIT - 1) {
            STAGE_K(cur ^ 1, (it + 1) * KT);
        } else {  // last iter: pre-stage phase-2's first tiles
            STAGE_K(cur ^ 1, 0);
            STAGE_V(cur ^ 1, 0);
        }
        const int k0 = it * KT;
#pragma unroll
        for (int nt = 0; nt < 2; ++nt) {
            f32x4 acc = {0.f, 0.f, 0.f, 0.f};
#pragma unroll
            for (int kd = 0; kd < 4; ++kd) {
                bf16x8 bk = *(const bf16x8*)(ldsK0 + (cur << 13) +
                                             ((nt * 16 + l16) << 8) +
                                             (((kd << 6) + (quad << 4)) ^ kswz));
                acc = __builtin_amdgcn_mfma_f32_16x16x32_bf16(aq[kd], bk, acc, 0, 0, 0);
            }
            const int col = k0 + nt * 16 + l16;
            const unsigned mw = maskT[mrowbase + (size_t)col * (Ss / 32) + qw];
#pragma unroll
            for (int r = 0; r < 4; ++r)
                rsum[r] += ((mw >> (bitbase + r)) & 1u) ? 0.f
                                                        : __expf(acc[r] * 0.0078125f);
        }
        __syncthreads();
    }

    // in-register reciprocal: after the 16-lane reduce, every lane holds the full
    // row sums for exactly the rows (quad*4+r) it will normalize — no LDS needed.
    float li[4];
#pragma unroll
    for (int r = 0; r < 4; ++r) {
        float v = rsum[r];
        v += __shfl_xor(v, 1, 16);
        v += __shfl_xor(v, 2, 16);
        v += __shfl_xor(v, 4, 16);
        v += __shfl_xor(v, 8, 16);
        li[r] = 1.0f / v;
    }

    // ---- phase 2: attn write + PV, prefetch-1-ahead ----
    f32x4 oacc[8];
#pragma unroll
    for (int dg = 0; dg < 8; ++dg) oacc[dg] = (f32x4){0.f, 0.f, 0.f, 0.f};

    char* myPs = (char*)&Ps[0][0][0] + (w << 11);

    for (int it = 0; it < NIT; ++it) {
        const int cur = it & 1;
        if (it < NIT - 1) {
            STAGE_K(cur ^ 1, (it + 1) * KT);
            STAGE_V(cur ^ 1, (it + 1) * KT);
        }
        const int k0 = it * KT;
#pragma unroll
        for (int nt = 0; nt < 2; ++nt) {
            f32x4 acc = {0.f, 0.f, 0.f, 0.f};
#pragma unroll
            for (int kd = 0; kd < 4; ++kd) {
                bf16x8 bk = *(const bf16x8*)(ldsK0 + (cur << 13) +
                                             ((nt * 16 + l16) << 8) +
                                             (((kd << 6) + (quad << 4)) ^ kswz));
                acc = __builtin_amdgcn_mfma_f32_16x16x32_bf16(aq[kd], bk, acc, 0, 0, 0);
            }
            const int col = k0 + nt * 16 + l16;
            const unsigned mw = maskT[mrowbase + (size_t)col * (Ss / 32) + qw];
#pragma unroll
            for (int r = 0; r < 4; ++r) {
                const int prow = (quad << 2) + r;
                float p = ((mw >> (bitbase + r)) & 1u)
                              ? 0.0f
                              : __expf(acc[r] * 0.0078125f) * li[r];
                attn[((size_t)(bh * Ss + q0 + (w << 4) + prow)) * Ss + col] = p;
                *(__bf16*)(myPs + (prow << 7) +
                           ((nt * 32 + (l16 << 1)) ^ ((prow & 7) << 4))) = (__bf16)p;
            }
        }
        // PV: wave-private LDS round-trip (same-wave DS ordering; no barrier)
        {
            bf16x8 ap = *(const bf16x8*)(myPs + (l16 << 7) + ((quad << 4) ^ kswz));
#pragma unroll
            for (int dg = 0; dg < 8; ++dg) {
                bf16x8 bv = *(const bf16x8*)(ldsV0 + (cur << 13) +
                                             ((dg * 16 + l16) << 6) +
                                             ((quad << 4) ^ vswz));
                oacc[dg] = __builtin_amdgcn_mfma_f32_16x16x32_bf16(ap, bv, oacc[dg], 0, 0, 0);
            }
        }
        __syncthreads();
    }

    // epilogue
#pragma unroll
    for (int dg = 0; dg < 8; ++dg)
#pragma unroll
        for (int r = 0; r < 4; ++r)
            out[((size_t)(bh * Ss + q0 + (w << 4) + (quad << 2) + r)) * Dd + dg * 16 +
                l16] = oacc[dg][r];
}

extern "C" void kernel_launch(void* const* d_in, const int* in_sizes, int n_in,
                              void* d_out, int out_size, void* d_ws, size_t ws_size,
                              hipStream_t stream) {
    const float* Q = (const float*)d_in[0];
    const float* K = (const float*)d_in[1];
    const float* V = (const float*)d_in[2];
    const float* M = (const float*)d_in[3];

    float* out = (float*)d_out;                     // B*H*S*D floats
    float* attn = out + (size_t)Bb * Hh * Ss * Dd;  // then B*H*S*S

    // workspace layout (~98 MB)
    char* ws = (char*)d_ws;
    __bf16* Qb = (__bf16*)ws;                       // 33,554,432 B
    __bf16* Kb = (__bf16*)(ws + 33554432);          // 33,554,432 B
    __bf16* VTb = (__bf16*)(ws + 67108864);         // 33,554,432 B
    unsigned* maskT = (unsigned*)(ws + 100663296);  // 2,097,152 B

    k_cvt<<<16384, 256, 0, stream>>>((const float4*)Q, (const float4*)K,
                                     (bf16x4*)Qb, (bf16x4*)Kb);
    k_vt<<<dim3(32, 2, 64), 256, 0, stream>>>(V, VTb);
    k_mask<<<dim3(32, 32, 4), 256, 0, stream>>>(M, maskT);
    attn_kernel<<<dim3(32, 64), 256, 0, stream>>>(Qb, Kb, VTb, maskT, out, attn);
}

// Round 3
// 1679.669 us; speedup vs baseline: 1.0794x; 1.0623x over previous
//
#include <hip/hip_runtime.h>

// Shapes (fixed by the reference)
#define Bb 4
#define Hh 16
#define Ss 2048
#define Dd 128
#define KT 32          // k-tile columns per iteration
#define NIT (Ss / KT)  // 64 iterations per phase

typedef __bf16 bf16x8 __attribute__((ext_vector_type(8)));
typedef __bf16 bf16x4 __attribute__((ext_vector_type(4)));
typedef float f32x4 __attribute__((ext_vector_type(4)));

// ---------- prep: fp32 -> bf16 flat for Q and K ----------
__global__ void k_cvt(const float4* __restrict__ Q, const float4* __restrict__ K,
                      bf16x4* __restrict__ Qb, bf16x4* __restrict__ Kb) {
    size_t i = (size_t)blockIdx.x * 256 + threadIdx.x;
    float4 q = Q[i], k = K[i];
    Qb[i] = (bf16x4){(__bf16)q.x, (__bf16)q.y, (__bf16)q.z, (__bf16)q.w};
    Kb[i] = (bf16x4){(__bf16)k.x, (__bf16)k.y, (__bf16)k.z, (__bf16)k.w};
}

// ---------- prep: V fp32 [bh][k][d] -> bf16 V^T [bh][d][k] ----------
__global__ void k_vt(const float* __restrict__ V, __bf16* __restrict__ VT) {
    __shared__ __bf16 lds[64][65];
    int k0 = blockIdx.x * 64, d0 = blockIdx.y * 64, bh = blockIdx.z;
    int t = threadIdx.x;
    for (int i = 0; i < 16; ++i) {
        int idx = i * 256 + t;
        int kl = idx >> 6, dl = idx & 63;
        lds[kl][dl] = (__bf16)V[((size_t)(bh * Ss + k0 + kl)) * Dd + d0 + dl];
    }
    __syncthreads();
    for (int i = 0; i < 16; ++i) {
        int idx = i * 256 + t;
        int dl = idx >> 6, kl = idx & 63;
        VT[((size_t)(bh * Dd + d0 + dl)) * Ss + k0 + kl] = lds[kl][dl];
    }
}

// ---------- prep: mask fp32 [b][q][k] -> bits maskT[b][k][q/32] (bit=1 => masked) ----------
__global__ void k_mask(const float* __restrict__ M, unsigned* __restrict__ maskT) {
    __shared__ unsigned char lds[64][68];
    int k0 = blockIdx.x * 64, q0 = blockIdx.y * 64, b = blockIdx.z;
    int t = threadIdx.x;
    for (int i = 0; i < 16; ++i) {
        int idx = i * 256 + t;
        int ql = idx >> 6, kl = idx & 63;
        lds[ql][kl] = (M[((size_t)(b * Ss + q0 + ql)) * Ss + k0 + kl] != 0.0f) ? 1 : 0;
    }
    __syncthreads();
    if (t < 128) {
        int kl = t >> 1, wsel = t & 1;
        unsigned wv = 0;
        for (int j = 0; j < 32; ++j)
            wv |= ((unsigned)lds[wsel * 32 + j][kl]) << j;
        maskT[((size_t)(b * Ss + k0 + kl)) * (Ss / 32) + (q0 >> 5) + wsel] = wv;
    }
}

// async 16B global->LDS copy (LDS dest: wave-uniform base + lane*16)
__device__ __forceinline__ void gl2lds16(const void* g, void* l) {
    __builtin_amdgcn_global_load_lds(
        (const __attribute__((address_space(1))) unsigned int*)g,
        (__attribute__((address_space(3))) unsigned int*)l, 16, 0, 0);
}

// ---------- main fused attention ----------
// grid (32, 64), block 256 (4 waves). Each block: 64 q-rows, full K sweep x2.
// LDS = 2*8K (K dbuf) + 2*8K (V^T dbuf) + 8K (Ps) = 40960 B exactly -> 4 blocks/CU.
__global__ __launch_bounds__(256, 4) void attn_kernel(
    const __bf16* __restrict__ Qb, const __bf16* __restrict__ Kb,
    const __bf16* __restrict__ VTb, const unsigned* __restrict__ maskT,
    float* __restrict__ out, float* __restrict__ attn) {
    __shared__ __align__(16) __bf16 Ks[2][KT][Dd];   // 2 x 8192 B, XOR-swizzled contents
    __shared__ __align__(16) __bf16 VTs[2][Dd][KT];  // 2 x 8192 B, XOR-swizzled contents
    __shared__ __align__(16) __bf16 Ps[4][16][64];   // per-wave P bridge (32 cols, swizzled)

    const int t = threadIdx.x;
    const int w = t >> 6, lane = t & 63, quad = lane >> 4, l16 = lane & 15;

    // XCD-aware remap: 2048 wgs, 8 XCDs; XCD x gets bh in [8x,8x+8) with all 32 q-blocks
    const int wg = (int)blockIdx.x + ((int)blockIdx.y << 5);
    const int nid = ((wg & 7) << 8) + (wg >> 3);
    const int q0 = (nid & 31) << 6;
    const int bh = nid >> 5;
    const int b = bh >> 4;

    const __bf16* Kbh = Kb + (size_t)bh * (Ss * Dd);
    const char* Vbh = (const char*)(VTb + (size_t)bh * ((size_t)Dd * Ss));

    // staging geometry (linear LDS dest; inverse-swizzle applied to the GLOBAL source)
    const int ksub = t >> 4;                                   // K row within 16-row chunk
    const int kcb = ((t & 15) << 4) ^ ((ksub & 7) << 4);       // K source col bytes
    const int vsub = t >> 2;                                   // V row within 64-row chunk
    const int vcb = ((t & 3) << 4) ^ ((vsub & 3) << 4);        // V source col bytes
    char* ldsKbase = (char*)&Ks[0][0][0] + (w << 10);          // wave-uniform
    char* ldsVbase = (char*)&VTs[0][0][0] + (w << 10);

// buffer stride = 8192 B (<<13) — per-buffer size of Ks/VTs
#define STAGE_K(buf, k0_)                                                      \
    {                                                                          \
        const char* gb = (const char*)(Kbh + (size_t)(k0_) * Dd) + kcb;        \
        _Pragma("unroll") for (int i_ = 0; i_ < 2; ++i_)                       \
            gl2lds16(gb + ((i_ << 4) + ksub) * 256,                            \
                     ldsKbase + ((buf) << 13) + (i_ << 12));                   \
    }
#define STAGE_V(buf, k0_)                                                      \
    {                                                                          \
        const char* gb = Vbh + (size_t)(k0_) * 2 + vcb;                        \
        _Pragma("unroll") for (int i_ = 0; i_ < 2; ++i_)                       \
            gl2lds16(gb + (size_t)((i_ << 6) + vsub) * (Ss * 2),               \
                     ldsVbase + ((buf) << 13) + (i_ << 12));                   \
    }

    // Q fragments straight from global (no LDS staging for Q)
    bf16x8 aq[4];
    {
        STAGE_K(0, 0);
        const __bf16* qp =
            Qb + ((size_t)(bh * Ss + q0 + (w << 4) + l16)) * Dd + (quad << 3);
#pragma unroll
        for (int kd = 0; kd < 4; ++kd) aq[kd] = *(const bf16x8*)(qp + (kd << 5));
    }
    __syncthreads();  // drains vmcnt: K tile 0 resident

    const char* ldsK0 = (const char*)&Ks[0][0][0];
    const char* ldsV0 = (const char*)&VTs[0][0][0];
    const int kswz = (l16 & 7) << 4;
    const int vswz = (l16 & 3) << 4;

    const int qw = (q0 >> 5) + (w >> 1);
    const int bitbase = ((w & 1) << 4) + (quad << 2);
    const size_t mrowbase = (size_t)b * Ss * (Ss / 32);
    // mask word address for (iter, nt): mrowbase + (iter*KT + nt*16 + l16)*(Ss/32) + qw
    const unsigned* mbase = maskT + mrowbase + (size_t)l16 * (Ss / 32) + qw;
#define MASK_AT(it_, nt_) mbase[((it_)*KT + (nt_)*16) * (Ss / 32)]

    // ---- phase 1: row sums of exp(scores) ----
    // mask words rotated one iteration ahead (issued BEFORE stage loads so no
    // mid-iteration vmcnt wait ever lands on the prefetch).
    float rsum[4] = {0.f, 0.f, 0.f, 0.f};
    unsigned mc0 = MASK_AT(0, 0), mc1 = MASK_AT(0, 1);
    for (int it = 0; it < NIT; ++it) {
        const int cur = it & 1;
        const int itn = (it + 1 < NIT) ? it + 1 : 0;
        unsigned mn0 = MASK_AT(itn, 0);  // prefetch next-iter mask first
        unsigned mn1 = MASK_AT(itn, 1);
        if (it < NIT - 1) {
            STAGE_K(cur ^ 1, (it + 1) * KT);
        } else {  // last iter: pre-stage phase-2's first tiles
            STAGE_K(cur ^ 1, 0);
            STAGE_V(cur ^ 1, 0);
        }
#pragma unroll
        for (int nt = 0; nt < 2; ++nt) {
            f32x4 acc = {0.f, 0.f, 0.f, 0.f};
            __builtin_amdgcn_s_setprio(1);
#pragma unroll
            for (int kd = 0; kd < 4; ++kd) {
                bf16x8 bk = *(const bf16x8*)(ldsK0 + (cur << 13) +
                                             ((nt * 16 + l16) << 8) +
                                             (((kd << 6) + (quad << 4)) ^ kswz));
                acc = __builtin_amdgcn_mfma_f32_16x16x32_bf16(aq[kd], bk, acc, 0, 0, 0);
            }
            __builtin_amdgcn_s_setprio(0);
            const unsigned mw = nt ? mc1 : mc0;
#pragma unroll
            for (int r = 0; r < 4; ++r)
                rsum[r] += ((mw >> (bitbase + r)) & 1u) ? 0.f
                                                        : __expf(acc[r] * 0.0078125f);
        }
        __syncthreads();
        mc0 = mn0;
        mc1 = mn1;
    }

    // in-register reciprocal: after the 16-lane reduce, every lane holds the full
    // row sums for exactly the rows (quad*4+r) it will normalize — no LDS needed.
    float li[4];
#pragma unroll
    for (int r = 0; r < 4; ++r) {
        float v = rsum[r];
        v += __shfl_xor(v, 1, 16);
        v += __shfl_xor(v, 2, 16);
        v += __shfl_xor(v, 4, 16);
        v += __shfl_xor(v, 8, 16);
        li[r] = 1.0f / v;
    }

    // ---- phase 2: attn write + PV ----
    f32x4 oacc[8];
#pragma unroll
    for (int dg = 0; dg < 8; ++dg) oacc[dg] = (f32x4){0.f, 0.f, 0.f, 0.f};

    char* myPs = (char*)&Ps[0][0][0] + (w << 11);

    mc0 = MASK_AT(0, 0);
    mc1 = MASK_AT(0, 1);
    for (int it = 0; it < NIT; ++it) {
        const int cur = it & 1;
        const int itn = (it + 1 < NIT) ? it + 1 : 0;
        unsigned mn0 = MASK_AT(itn, 0);  // 2 mask loads first,
        unsigned mn1 = MASK_AT(itn, 1);
        if (it < NIT - 1) {              // then 4 stage loads,
            STAGE_K(cur ^ 1, (it + 1) * KT);
            STAGE_V(cur ^ 1, (it + 1) * KT);
        }
        const int k0 = it * KT;
#pragma unroll
        for (int nt = 0; nt < 2; ++nt) {
            f32x4 acc = {0.f, 0.f, 0.f, 0.f};
            __builtin_amdgcn_s_setprio(1);
#pragma unroll
            for (int kd = 0; kd < 4; ++kd) {
                bf16x8 bk = *(const bf16x8*)(ldsK0 + (cur << 13) +
                                             ((nt * 16 + l16) << 8) +
                                             (((kd << 6) + (quad << 4)) ^ kswz));
                acc = __builtin_amdgcn_mfma_f32_16x16x32_bf16(aq[kd], bk, acc, 0, 0, 0);
            }
            __builtin_amdgcn_s_setprio(0);
            const int col = k0 + nt * 16 + l16;
            const unsigned mw = nt ? mc1 : mc0;
#pragma unroll
            for (int r = 0; r < 4; ++r) {
                const int prow = (quad << 2) + r;
                float p = ((mw >> (bitbase + r)) & 1u)
                              ? 0.0f
                              : __expf(acc[r] * 0.0078125f) * li[r];
                attn[((size_t)(bh * Ss + q0 + (w << 4) + prow)) * Ss + col] = p;  // 8 stores
                *(__bf16*)(myPs + (prow << 7) +
                           ((nt * 32 + (l16 << 1)) ^ ((prow & 7) << 4))) = (__bf16)p;
            }
        }
        // PV: wave-private LDS round-trip (same-wave DS ordering; no barrier)
        {
            bf16x8 ap = *(const bf16x8*)(myPs + (l16 << 7) + ((quad << 4) ^ kswz));
            __builtin_amdgcn_s_setprio(1);
#pragma unroll
            for (int dg = 0; dg < 8; ++dg) {
                bf16x8 bv = *(const bf16x8*)(ldsV0 + (cur << 13) +
                                             ((dg * 16 + l16) << 6) +
                                             ((quad << 4) ^ vswz));
                oacc[dg] = __builtin_amdgcn_mfma_f32_16x16x32_bf16(ap, bv, oacc[dg], 0, 0, 0);
            }
            __builtin_amdgcn_s_setprio(0);
        }
        // counted-wait barrier (T4): per-iter VMEM issue order is
        // {2 mask loads, 4 stage loads, 8 attn stores}. vmcnt(8) retires mask+stage
        // (in-order retirement) while the 8 stores stay in flight across the barrier.
        asm volatile("s_waitcnt vmcnt(8)" ::: "memory");
        __builtin_amdgcn_s_barrier();
        __builtin_amdgcn_sched_barrier(0);
        mc0 = mn0;
        mc1 = mn1;
    }

    // epilogue
#pragma unroll
    for (int dg = 0; dg < 8; ++dg)
#pragma unroll
        for (int r = 0; r < 4; ++r)
            out[((size_t)(bh * Ss + q0 + (w << 4) + (quad << 2) + r)) * Dd + dg * 16 +
                l16] = oacc[dg][r];
}

extern "C" void kernel_launch(void* const* d_in, const int* in_sizes, int n_in,
                              void* d_out, int out_size, void* d_ws, size_t ws_size,
                              hipStream_t stream) {
    const float* Q = (const float*)d_in[0];
    const float* K = (const float*)d_in[1];
    const float* V = (const float*)d_in[2];
    const float* M = (const float*)d_in[3];

    float* out = (float*)d_out;                     // B*H*S*D floats
    float* attn = out + (size_t)Bb * Hh * Ss * Dd;  // then B*H*S*S

    // workspace layout (~98 MB)
    char* ws = (char*)d_ws;
    __bf16* Qb = (__bf16*)ws;                       // 33,554,432 B
    __bf16* Kb = (__bf16*)(ws + 33554432);          // 33,554,432 B
    __bf16* VTb = (__bf16*)(ws + 67108864);         // 33,554,432 B
    unsigned* maskT = (unsigned*)(ws + 100663296);  // 2,097,152 B

    k_cvt<<<16384, 256, 0, stream>>>((const float4*)Q, (const float4*)K,
                                     (bf16x4*)Qb, (bf16x4*)Kb);
    k_vt<<<dim3(32, 2, 64), 256, 0, stream>>>(V, VTb);
    k_mask<<<dim3(32, 32, 4), 256, 0, stream>>>(M, maskT);
    attn_kernel<<<dim3(32, 64), 256, 0, stream>>>(Qb, Kb, VTb, maskT, out, attn);
}